// Round 2
// baseline (6090.545 us; speedup 1.0000x reference)
//
#include <hip/hip_runtime.h>

#define B_   64
#define T_   512
#define DIN  300
#define H_   512
#define G3   1536   // 3*H
#define TWOH 1024
#define R_   256
#define KX   320    // DIN padded to mult of 32

typedef __attribute__((ext_vector_type(8))) short short8;
typedef __attribute__((ext_vector_type(4))) float f32x4;

__device__ __forceinline__ unsigned short f2bf(float f) {
  union { float f; unsigned int u; } v; v.f = f;
  unsigned int u = v.u;
  u += 0x7fffu + ((u >> 16) & 1u);   // RTN
  return (unsigned short)(u >> 16);
}
__device__ __forceinline__ float bf2f(unsigned short h) {
  union { unsigned int u; float f; } v; v.u = ((unsigned int)h) << 16;
  return v.f;
}

// ---------------------------------------------------------------------------
// K0: X fp32 [B,T,300] -> Xbf bf16 [B,T,320] (zero-padded cols 300..319)
// ---------------------------------------------------------------------------
__global__ __launch_bounds__(256) void k_xbf(
    const float* __restrict__ X, unsigned short* __restrict__ Xbf)
{
  const int id = blockIdx.x * 256 + threadIdx.x;      // B*T*40 items
  if (id >= B_ * T_ * 40) return;
  const int row = id / 40, c = id % 40, k = c * 8;
  const float* src = X + (long long)row * DIN + k;
  short8 v;
#pragma unroll
  for (int i = 0; i < 8; ++i)
    v[i] = (short)((k + i < DIN) ? f2bf(src[i]) : (unsigned short)0);
  *(short8*)(Xbf + (long long)row * KX + k) = v;
}

// ---------------------------------------------------------------------------
// K1: persistent bidirectional GRU with fused input projection.
// 128 blocks x 384 thr (6 waves). Group g7 = bid&7 = (dir, batch-chunk of 16);
// 16 blocks/group each own 32 hidden units (ub = bid>>3).
// Weights live in VGPRs as MFMA B-frags: wh[16] (Whh slice, K=512) and
// wx[10] (Wih slice, K=320). Per step, per wave (gate gt, unit-half uh):
//   acc_x = x_te . Wih^T   (independent of other blocks -> issued pre-wait)
//   acc_h = h_{t-1} . Whh^T (A rows read from hcat[t-/+1]; rows past a
//           sequence's length read 0 instead of frozen h — harmless, the
//           valid-mask discards exactly those gh rows)
// fp32 carried state in LDS; h published ONLY via hcat (bf16); group sync via
// agent-scope release fetch_add / relaxed poll + acquire fence. hcat[te] is
// written once and never rewritten, so no double buffer is needed.
// ---------------------------------------------------------------------------
__global__ __launch_bounds__(384) void k_gru(
    const unsigned short* __restrict__ Xbf,
    const float* __restrict__ Wih_f, const float* __restrict__ Whh_f,
    const float* __restrict__ bih_f, const float* __restrict__ bhh_f,
    const float* __restrict__ Wih_b, const float* __restrict__ Whh_b,
    const float* __restrict__ bih_b, const float* __restrict__ bhh_b,
    const int*  __restrict__ lens,
    unsigned short* __restrict__ hcat,        // [B][T][1024] bf16
    unsigned int* __restrict__ cnt)           // [8][512]
{
  const int bid = blockIdx.x;
  const int g7 = bid & 7, ub = bid >> 3;
  const int dir = g7 & 1, bc = g7 >> 1;
  const int b0 = bc * 16, u0 = ub * 32;
  const int tid = threadIdx.x;
  const int wv = tid >> 6, ln = tid & 63, lr = ln & 15, lq = ln >> 4;
  const int gt = wv >> 1, uh = wv & 1;       // gate 0..2, unit-half 0..1

  const float* Wih = dir ? Wih_b : Wih_f;
  const float* Whh = dir ? Whh_b : Whh_f;
  const float* bih = dir ? bih_b : bih_f;
  const float* bhh = dir ? bhh_b : bhh_f;

  __shared__ float ghx_s[96 * 17];   // x-path gh, [local gate row][batch]
  __shared__ float ghh_s[96 * 17];   // h-path gh
  __shared__ float h_s[16 * 32];     // exact fp32 carried state
  __shared__ float bih_s[96], bhh_s[96];
  __shared__ int   lens_s[16];

  for (int i = tid; i < 16 * 32; i += 384) h_s[i] = 0.f;
  if (tid < 96) {
    bih_s[tid] = bih[(tid / 32) * H_ + u0 + (tid % 32)];
    bhh_s[tid] = bhh[(tid / 32) * H_ + u0 + (tid % 32)];
  }
  if (tid < 16) lens_s[tid] = lens[b0 + tid];

  // ---- persistent B-fragments (col = lr = gate row; k = lq*8+i) ----
  const int grow = gt * H_ + u0 + uh * 16 + lr;
  short8 wh[16], wx[10];
  {
    const float* wr = Whh + (long long)grow * H_;
#pragma unroll
    for (int kk = 0; kk < 16; ++kk) {
      const int k = kk * 32 + lq * 8;
      const float4 x0 = *(const float4*)(wr + k);
      const float4 x1 = *(const float4*)(wr + k + 4);
      short8 f;
      f[0] = (short)f2bf(x0.x); f[1] = (short)f2bf(x0.y);
      f[2] = (short)f2bf(x0.z); f[3] = (short)f2bf(x0.w);
      f[4] = (short)f2bf(x1.x); f[5] = (short)f2bf(x1.y);
      f[6] = (short)f2bf(x1.z); f[7] = (short)f2bf(x1.w);
      wh[kk] = f;
    }
    const float* wr2 = Wih + (long long)grow * DIN;
#pragma unroll
    for (int kk = 0; kk < 10; ++kk) {
      const int k = kk * 32 + lq * 8;
      short8 f;
#pragma unroll
      for (int i = 0; i < 8; ++i) {
        const float v = (k + i < DIN) ? wr2[k + i] : 0.f;
        f[i] = (short)f2bf(v);
      }
      wx[kk] = f;
    }
  }
  __syncthreads();

  for (int t = 0; t < T_; ++t) {
    const int te = dir ? (T_ - 1 - t) : t;

    // ---- x-path MFMAs: independent of the inter-block flag ----
    f32x4 accx = (f32x4){0.f, 0.f, 0.f, 0.f};
    {
      const unsigned short* xb = Xbf + ((long long)(b0 + lr) * T_ + te) * KX;
#pragma unroll
      for (int kk = 0; kk < 10; ++kk) {
        const short8 a = *(const short8*)(xb + kk * 32 + lq * 8);
        accx = __builtin_amdgcn_mfma_f32_16x16x32_bf16(a, wx[kk], accx, 0, 0, 0);
      }
    }

    // ---- wait for group step t-1, then h-path MFMAs ----
    f32x4 acch = (f32x4){0.f, 0.f, 0.f, 0.f};
    if (t > 0) {
      if (tid == 0) {
        while (__hip_atomic_load(&cnt[g7 * T_ + t - 1], __ATOMIC_RELAXED,
                                 __HIP_MEMORY_SCOPE_AGENT) < 16u)
          __builtin_amdgcn_s_sleep(2);
      }
      __syncthreads();
      __builtin_amdgcn_fence(__ATOMIC_ACQUIRE, "agent");  // inv L1/L2

      const int tp = dir ? (te + 1) : (te - 1);
      const unsigned short* hb =
          hcat + ((long long)(b0 + lr) * T_ + tp) * TWOH + dir * H_;
#pragma unroll
      for (int kk = 0; kk < 16; ++kk) {
        const short8 a = *(const short8*)(hb + kk * 32 + lq * 8);
        acch = __builtin_amdgcn_mfma_f32_16x16x32_bf16(a, wh[kk], acch, 0, 0, 0);
      }
    }

    // ---- scatter both partial gh (D: col=lr -> gate, row=lq*4+r -> batch) --
    {
      const int lrow = gt * 32 + uh * 16 + lr;
#pragma unroll
      for (int r = 0; r < 4; ++r) {
        ghx_s[lrow * 17 + lq * 4 + r] = accx[r];
        ghh_s[lrow * 17 + lq * 4 + r] = acch[r];
      }
    }
    __syncthreads();

    // ---- elementwise: 512 (u,b) items over 384 threads ----
#pragma unroll
    for (int it = 0; it < 2; ++it) {
      const int idx = tid + it * 384;
      if (idx < 512) {
        const int u = idx & 31, lb = idx >> 5;
        const float xr = ghx_s[u * 17 + lb]        + bih_s[u];
        const float xz = ghx_s[(32 + u) * 17 + lb] + bih_s[32 + u];
        const float xn = ghx_s[(64 + u) * 17 + lb] + bih_s[64 + u];
        const float gr = ghh_s[u * 17 + lb]        + bhh_s[u];
        const float gz = ghh_s[(32 + u) * 17 + lb] + bhh_s[32 + u];
        const float gn = ghh_s[(64 + u) * 17 + lb] + bhh_s[64 + u];
        const float h_old = h_s[lb * 32 + u];
        const float rg = 1.f / (1.f + __expf(-(xr + gr)));
        const float zg = 1.f / (1.f + __expf(-(xz + gz)));
        const float ng = tanhf(xn + rg * gn);
        const float hn = (1.f - zg) * ng + zg * h_old;
        const bool valid = te < lens_s[lb];
        const float hc = valid ? hn : h_old;
        h_s[lb * 32 + u] = hc;
        hcat[((long long)(b0 + lb) * T_ + te) * TWOH + dir * H_ + u0 + u] =
            f2bf(valid ? hc : 0.f);
      }
    }
    __syncthreads();   // per-wave vmcnt(0) before barrier: stores complete
    if (tid == 0)
      __hip_atomic_fetch_add(&cnt[g7 * T_ + t], 1u, __ATOMIC_RELEASE,
                             __HIP_MEMORY_SCOPE_AGENT);
  }
}

// ---------------------------------------------------------------------------
// K2: scores[b,t] = sum_r u_s[r] * tanh(Hcat[b,t,:] . g2r_W[r,:] + g2r_b[r])
// Block = 64 M-rows x full N=256, K=1024; reduce over r in-register.
// ---------------------------------------------------------------------------
__global__ __launch_bounds__(256) void k_scores(
    const unsigned short* __restrict__ hcat,   // [B*T][1024] bf16
    const float* __restrict__ g2rW,            // [256][1024]
    const float* __restrict__ g2rb,
    const float* __restrict__ us,
    float* __restrict__ scores)
{
  const int m0 = blockIdx.x * 64;
  const int tid = threadIdx.x;
  const int wv = tid >> 6, ln = tid & 63, lr = ln & 15, lq = ln >> 4;

  __shared__ unsigned short As[64 * 40];
  __shared__ unsigned short Bs[256 * 40];

  f32x4 acc[16];
#pragma unroll
  for (int j = 0; j < 16; ++j) acc[j] = (f32x4){0.f, 0.f, 0.f, 0.f};

  for (int kt = 0; kt < 32; ++kt) {
    const int k0 = kt * 32;
    __syncthreads();
#pragma unroll
    for (int h = 0; h < 2; ++h) {            // A: 64 rows x 32 bf16
      const int id = tid * 2 + h;
      const int row = id >> 3, kq = id & 7;
      *(uint2*)&As[row * 40 + kq * 4] =
          *(const uint2*)(hcat + (long long)(m0 + row) * TWOH + k0 + kq * 4);
    }
    {
      const float* src = g2rW + (long long)tid * TWOH + k0;
#pragma unroll
      for (int h = 0; h < 4; ++h) {          // B row = tid: 32 floats -> bf16
        const float4 v0 = *(const float4*)(src + h * 8);
        const float4 v1 = *(const float4*)(src + h * 8 + 4);
        short8 f;
        f[0] = (short)f2bf(v0.x); f[1] = (short)f2bf(v0.y);
        f[2] = (short)f2bf(v0.z); f[3] = (short)f2bf(v0.w);
        f[4] = (short)f2bf(v1.x); f[5] = (short)f2bf(v1.y);
        f[6] = (short)f2bf(v1.z); f[7] = (short)f2bf(v1.w);
        *(short8*)&Bs[tid * 40 + h * 8] = f;
      }
    }
    __syncthreads();
    const short8 a = *(const short8*)&As[(wv * 16 + lr) * 40 + lq * 8];
#pragma unroll
    for (int j = 0; j < 16; ++j) {
      const short8 b = *(const short8*)&Bs[(j * 16 + lr) * 40 + lq * 8];
      acc[j] = __builtin_amdgcn_mfma_f32_16x16x32_bf16(a, b, acc[j], 0, 0, 0);
    }
  }

  float part[4] = {0.f, 0.f, 0.f, 0.f};
#pragma unroll
  for (int j = 0; j < 16; ++j) {
    const int col = j * 16 + lr;
    const float bias = g2rb[col];
    const float uw = us[col];
#pragma unroll
    for (int r = 0; r < 4; ++r) part[r] += tanhf(acc[j][r] + bias) * uw;
  }
#pragma unroll
  for (int d = 1; d < 16; d <<= 1) {
#pragma unroll
    for (int r = 0; r < 4; ++r) part[r] += __shfl_xor(part[r], d, 64);
  }
  if (lr == 0) {
#pragma unroll
    for (int r = 0; r < 4; ++r) scores[m0 + wv * 16 + lq * 4 + r] = part[r];
  }
}

// ---------------------------------------------------------------------------
// K3: masked softmax over t per batch (block = batch, 512 threads)
// ---------------------------------------------------------------------------
__global__ __launch_bounds__(512) void k_softmax(
    const float* __restrict__ scores, const int* __restrict__ lens,
    float* __restrict__ wout)
{
  const int b = blockIdx.x;
  const int tid = threadIdx.x, ln = tid & 63, wid = tid >> 6;
  __shared__ float red[8];
  __shared__ float bcast;

  float s = scores[b * T_ + tid];
  if (tid >= lens[b]) s = -1e30f;

  float m = s;
#pragma unroll
  for (int d = 32; d; d >>= 1) m = fmaxf(m, __shfl_xor(m, d, 64));
  if (!ln) red[wid] = m;
  __syncthreads();
  if (tid == 0) {
    float mm = red[0];
#pragma unroll
    for (int i = 1; i < 8; ++i) mm = fmaxf(mm, red[i]);
    bcast = mm;
  }
  __syncthreads();
  const float mx = bcast;

  float e = __expf(s - mx);
  float sum = e;
#pragma unroll
  for (int d = 32; d; d >>= 1) sum += __shfl_xor(sum, d, 64);
  __syncthreads();
  if (!ln) red[wid] = sum;
  __syncthreads();
  if (tid == 0) {
    float ss = 0.f;
#pragma unroll
    for (int i = 0; i < 8; ++i) ss += red[i];
    bcast = ss;
  }
  __syncthreads();
  wout[b * T_ + tid] = e / bcast;
}

// ---------------------------------------------------------------------------
// K4: pooled[b][h] += sum_t w[b,t] * Hcat[b,t,h]   (block = (b, t-chunk 128))
// ---------------------------------------------------------------------------
__global__ __launch_bounds__(256) void k_pool(
    const unsigned short* __restrict__ hcat, const float* __restrict__ wsm,
    float* __restrict__ pooled)
{
  const int b = blockIdx.x >> 2, tc = blockIdx.x & 3;
  const int t0 = tc * 128;
  const int tid = threadIdx.x;
  __shared__ float w_s[128];
  if (tid < 128) w_s[tid] = wsm[b * T_ + t0 + tid];
  __syncthreads();
#pragma unroll
  for (int hc = 0; hc < 4; ++hc) {
    const int h = hc * 256 + tid;
    float acc = 0.f;
    for (int tt = 0; tt < 128; ++tt)
      acc += w_s[tt] * bf2f(hcat[((long long)b * T_ + t0 + tt) * TWOH + h]);
    atomicAdd(&pooled[b * TWOH + h], acc);
  }
}

// ---------------------------------------------------------------------------
// K5: out[b] = sigmoid(pooled[b] . r2o_W + r2o_b)
// ---------------------------------------------------------------------------
__global__ __launch_bounds__(256) void k_out(
    const float* __restrict__ pooled, const float* __restrict__ r2oW,
    const float* __restrict__ r2ob, float* __restrict__ out)
{
  const int b = blockIdx.x;
  const int tid = threadIdx.x, ln = tid & 63, wid = tid >> 6;
  __shared__ float red[4];
  float a = 0.f;
  for (int h = tid; h < TWOH; h += 256) a += pooled[b * TWOH + h] * r2oW[h];
#pragma unroll
  for (int d = 32; d; d >>= 1) a += __shfl_xor(a, d, 64);
  if (!ln) red[wid] = a;
  __syncthreads();
  if (tid == 0) {
    const float s = red[0] + red[1] + red[2] + red[3] + r2ob[0];
    out[b] = 1.f / (1.f + expf(-s));
  }
}

// ---------------------------------------------------------------------------
extern "C" void kernel_launch(void* const* d_in, const int* in_sizes, int n_in,
                              void* d_out, int out_size, void* d_ws, size_t ws_size,
                              hipStream_t stream) {
  const float* X     = (const float*)d_in[0];
  const int*   lens  = (const int*)d_in[1];
  const float* Wih_f = (const float*)d_in[3];
  const float* Whh_f = (const float*)d_in[4];
  const float* bih_f = (const float*)d_in[5];
  const float* bhh_f = (const float*)d_in[6];
  const float* Wih_b = (const float*)d_in[7];
  const float* Whh_b = (const float*)d_in[8];
  const float* bih_b = (const float*)d_in[9];
  const float* bhh_b = (const float*)d_in[10];
  const float* g2rW  = (const float*)d_in[11];
  const float* g2rb  = (const float*)d_in[12];
  const float* us    = (const float*)d_in[13];
  const float* r2oW  = (const float*)d_in[14];
  const float* r2ob  = (const float*)d_in[15];

  // workspace layout (non-overlapping, ~84.5 MiB total)
  char* ws = (char*)d_ws;
  unsigned short* Xbf    = (unsigned short*)(ws + 0LL);         // 20 MiB
  unsigned short* hcat   = (unsigned short*)(ws + 20971520LL);  // 64 MiB
  unsigned int*   cnt    = (unsigned int*)  (ws + 88080384LL);  // 16 KiB
  float*          scores = (float*)         (ws + 88096768LL);  // 128 KiB
  float*          wsm    = (float*)         (ws + 88227840LL);  // 128 KiB
  float*          pooled = (float*)         (ws + 88358912LL);  // 256 KiB
  if (ws_size < 88621056ULL) return;  // fail cleanly (absmax), don't scribble

  hipMemsetAsync(cnt, 0, 16384, stream);
  hipMemsetAsync(pooled, 0, 262144, stream);

  k_xbf<<<5120, 256, 0, stream>>>(X, Xbf);
  k_gru<<<128, 384, 0, stream>>>(Xbf, Wih_f, Whh_f, bih_f, bhh_f,
                                 Wih_b, Whh_b, bih_b, bhh_b, lens, hcat, cnt);
  k_scores<<<512, 256, 0, stream>>>(hcat, g2rW, g2rb, us, scores);
  k_softmax<<<64, 512, 0, stream>>>(scores, lens, wsm);
  k_pool<<<256, 256, 0, stream>>>(hcat, wsm, pooled);
  k_out<<<64, 256, 0, stream>>>(pooled, r2oW, r2ob, (float*)d_out);
}